// Round 1
// baseline (128.013 us; speedup 1.0000x reference)
//
#include <hip/hip_runtime.h>
#include <stdint.h>
#include <math.h>

// Problem shape (fixed by reference): xs [B,T,N,D] fp32, A [1,N,N] int32
#define BB 4
#define TT 32
#define NN 128
#define DD 32
#define NPB 16                       // nodes per block (16 nodes x 32 d = 512 threads)
#define TPB (NPB * DD)               // 512 threads
#define NBLK (BB * TT * (NN / NPB))  // 1024 blocks = exactly 4 per CU
#define CAP 16                       // band list capacity; selected-bin overflow -> exact fallback

// Temporal-candidate sentinel ids in the band list (real ids are 0..127).
#define SID_PREV 0xFFFEu
#define SID_NEXT 0xFFFFu

// Arithmetic 8-bin partition of the value axis. ANY monotone non-decreasing
// bin function gives exact rank selection (equal values -> equal bins, so
// bins partition the multiset in value order). Bins ~[-0.8+0.2b, -0.6+0.2b),
// ends open via clamp. Median of ~66 N(0,1) lands in interior bins with
// count <= CAP except ~1e-5/lane -> fallback is exact anyway.
__device__ __forceinline__ int bin8(float x) {
    int i = (int)fmaf(x, 5.0f, 4.0f);   // trunc; monotone non-decreasing
    i = i < 0 ? 0 : i;
    return i > 7 ? 7 : i;
}

// Build per-node compacted neighbor lists from A (+ implicit self loop).
__global__ __launch_bounds__(64) void build_adj_kernel(const int* __restrict__ A,
                                                       int* __restrict__ deg,
                                                       uint8_t* __restrict__ nbr) {
    const int n = blockIdx.x;
    const int lane = threadIdx.x;  // 0..63
    const int* arow = A + n * NN;
    uint8_t* row = nbr + n * NN;
    const int j0 = lane, j1 = lane + 64;
    const bool b0 = (arow[j0] != 0) || (j0 == n);
    const bool b1 = (arow[j1] != 0) || (j1 == n);
    const unsigned long long m0 = __ballot(b0);
    const unsigned long long m1 = __ballot(b1);
    const unsigned long long lmask = (1ULL << lane) - 1ULL;
    const int c0 = __popcll(m0);
    if (b0) row[__popcll(m0 & lmask)] = (uint8_t)j0;
    if (b1) row[c0 + __popcll(m1 & lmask)] = (uint8_t)j1;
    if (lane == 0) deg[n] = c0 + __popcll(m1);
}

// R(this): occupancy was the bottleneck (Occ 16%, VALUBusy 37%, HBM 1.8%).
// slist fp32 values -> u16 neighbor IDS (values re-fetched from sval with a
// masked address + 2 cndmask for temporal sentinels), and NPB 8->16 so the
// 16KB frame is amortized over 512 threads. LDS ~35.9KB -> 4 blocks x 8
// waves = 32 waves/CU (100% cap, was 50%); grid 1024 = exactly 4/CU.
// No waves/EU hint: a prior round showed it forces spills (2x regression).
__global__ __launch_bounds__(TPB) void median_kernel(const float* __restrict__ xs,
                                                     const int* __restrict__ deg,
                                                     const uint8_t* __restrict__ nbr,
                                                     float* __restrict__ out) {
    __shared__ float sval[NN * DD];             // 16 KB: current frame values
    __shared__ uint32_t snbr_w[NPB * NN / 4];   // 2 KB: neighbor id lists (u8)
    __shared__ int sdeg[NPB];
    __shared__ uint16_t slist[(CAP + 1) * TPB]; // 17 KB: band member IDS, column-major
                                                // u16 -> 2B/lane, 2-way bank = free

    const int tid = threadIdx.x;
    // Bijective XCD swizzle (NBLK % 8 == 0): each XCD gets a contiguous chunk
    // of 128 logical blocks = 16 whole frames -> frame re-reads are L2-local.
    const int bid = blockIdx.x;
    const int g = ((bid & 7) << 7) | (bid >> 3);
    const int ng = g & (NN / NPB - 1);       // % 8
    const int t  = (g >> 3) & (TT - 1);      // /8 % 32
    const int b  = g >> 8;                   // /256
    const int n0 = ng * NPB;

    const int d = tid & (DD - 1);
    const int nl = tid >> 5;  // local node 0..15
    const int n = n0 + nl;
    const int pv = (t > 0) ? 1 : 0;        // wave-uniform
    const int nv = (t < TT - 1) ? 1 : 0;   // wave-uniform
    const int ne = pv + nv;

    // temporal candidates as floats (coalesced; issued before the barrier)
    float exv0 = 0.0f, exv1 = 0.0f;
    if (pv) exv0 = xs[(((size_t)(b * TT + t - 1) * NN) + n) * DD + d];
    if (nv) {
        float v = xs[(((size_t)(b * TT + t + 1) * NN) + n) * DD + d];
        if (pv) exv1 = v; else exv0 = v;
    }

    // stage current frame (float4 coalesced, ds_write_b128): 1024 float4, 512 thr
    const float4* src4 = (const float4*)(xs + ((size_t)(b * TT + t) * NN) * DD);
    #pragma unroll
    for (int s = 0; s < 2; ++s) {
        int i4 = tid + (s << 9);
        ((float4*)sval)[i4] = src4[i4];
    }
    snbr_w[tid] = ((const uint32_t*)(nbr + (size_t)n0 * NN))[tid];  // exactly 512 words
    if (tid < NPB) sdeg[tid] = deg[n0 + tid];
    __syncthreads();

    const int dg = sdeg[nl];
    const int k = dg + ne;
    const uint32_t r = (uint32_t)((k - 1) >> 1);  // lower-median rank (0-based)
    const uint8_t* nb = (const uint8_t*)snbr_w + nl * NN;
    const float INFV = __uint_as_float(0x7F800000u);

    // ---- A1: one-pass 8-bin histogram, packed 8x8-bit in u64 ----
    unsigned long long pcnt = 0ull;
    {
        int j = 0;
        for (; j + 4 <= dg; j += 4) {
            uint32_t nw = *(const uint32_t*)(nb + j);
            #pragma unroll
            for (int q = 0; q < 4; ++q) {
                float x = sval[((nw >> (q * 8)) & 0xFFu) * DD + d];
                pcnt += 1ull << (bin8(x) * 8);
            }
        }
        for (; j < dg; ++j) {
            float x = sval[nb[j] * DD + d];
            pcnt += 1ull << (bin8(x) * 8);
        }
        if (ne >= 1) pcnt += 1ull << (bin8(exv0) * 8);
        if (ne == 2) pcnt += 1ull << (bin8(exv1) * 8);
    }

    // ---- prefix over 8 byte-counts; select bin containing rank r ----
    uint32_t cum = 0, lowcnt = 0, mexp = 0;
    int selbin = -1;
    #pragma unroll
    for (int bb = 0; bb < 8; ++bb) {
        uint32_t bc = (uint32_t)(pcnt >> (bb * 8)) & 0xFFu;
        uint32_t nc = cum + bc;
        if (selbin < 0 && r < nc) { selbin = bb; lowcnt = cum; mexp = bc; }
        cum = nc;
    }
    const bool fb = (mexp > CAP);          // only fallback: band too big
    const uint32_t rp = r - lowcnt;        // rank within band
    const int storebin = fb ? -1 : selbin; // fb lanes store nothing (mc stays 0)

    // ---- A2: branchless compaction of band member IDS (always-store; the
    // member's write is always the last write to its slot before mc advances) ----
    int mc = 0;
    {
        int j = 0;
        for (; j + 4 <= dg; j += 4) {
            uint32_t nw = *(const uint32_t*)(nb + j);
            #pragma unroll
            for (int q = 0; q < 4; ++q) {
                uint32_t id = (nw >> (q * 8)) & 0xFFu;
                float x = sval[id * DD + d];
                int slot = mc > CAP ? CAP : mc;
                slist[slot * TPB + tid] = (uint16_t)id;
                mc += (bin8(x) == storebin);
            }
        }
        for (; j < dg; ++j) {
            uint32_t id = nb[j];
            float x = sval[id * DD + d];
            int slot = mc > CAP ? CAP : mc;
            slist[slot * TPB + tid] = (uint16_t)id;
            mc += (bin8(x) == storebin);
        }
        if (ne >= 1) {
            int slot = mc > CAP ? CAP : mc;
            slist[slot * TPB + tid] = (uint16_t)SID_PREV;
            mc += (bin8(exv0) == storebin);
        }
        if (ne == 2) {
            int slot = mc > CAP ? CAP : mc;
            slist[slot * TPB + tid] = (uint16_t)SID_NEXT;
            mc += (bin8(exv1) == storebin);
        }
    }

    // band value fetch: id & 127 keeps even garbage/sentinel ids in-bounds;
    // sentinels override via cndmask. slist column tid is thread-private, so
    // no barrier needed between A2 writes and these reads (same-thread lgkmcnt).
    auto bandval = [&](int e) -> float {
        uint32_t id = slist[e * TPB + tid];
        float v = sval[(id & 127u) * DD + d];
        v = (id == SID_PREV) ? exv0 : v;
        v = (id == SID_NEXT) ? exv1 : v;
        return v;
    };

    // ---- B: single W=16 counting pass over the band (mc <= CAP) ----
    float ki[CAP];
    uint32_t cn[CAP];
    #pragma unroll
    for (int u = 0; u < CAP; ++u) {
        float v = bandval(u);
        ki[u] = (u < mc) ? v : INFV;
        cn[u] = 0;
    }
    int mm = mc;  // wave max -> uniform trip count
    #pragma unroll
    for (int off = 32; off; off >>= 1) {
        int o = __shfl_xor(mm, off);
        mm = mm > o ? mm : o;
    }
    for (int j = 0; j < mm; ++j) {
        float x = bandval(j);
        x = (j < mc) ? x : INFV;  // INF < ki never true
        #pragma unroll
        for (int u = 0; u < CAP; ++u) cn[u] += (x < ki[u]);
    }
    float result = 0.0f;
    bool found = fb;
    #pragma unroll
    for (int u = 0; u < CAP; ++u) {
        // strict-below count == rp identifies rank-rp exactly (unique per value)
        if (!found && u < mc && cn[u] == rp) { result = ki[u]; found = true; }
    }

    // ---- duplicate-median pass (exact multiset lower-median; ~never runs) ----
    if (__ballot(!found)) {
        uint32_t eq[CAP];
        #pragma unroll
        for (int u = 0; u < CAP; ++u) eq[u] = 0;
        for (int j = 0; j < mm; ++j) {
            float x = bandval(j);
            x = (j < mc) ? x : INFV;  // INF == finite ki is false
            #pragma unroll
            for (int u = 0; u < CAP; ++u) eq[u] += (x == ki[u]);
        }
        #pragma unroll
        for (int u = 0; u < CAP; ++u) {
            if (!found && u < mc && cn[u] <= rp && rp < cn[u] + eq[u]) {
                result = ki[u]; found = true;
            }
        }
    }

    // ---- full fallback (band > CAP; ~1e-5 of lanes): exact over all k ----
    if (__ballot(fb)) {
        bool done = !fb;
        for (int i0 = 0; __ballot(!done && i0 < k); i0 += 8) {
            float k8[8]; uint32_t c8[8];
            #pragma unroll
            for (int u = 0; u < 8; ++u) {
                int i = i0 + u;
                float sv = sval[nb[i & 127] * DD + d];
                float ev = ((i - dg) == 0) ? exv0 : exv1;
                float v = (i < dg) ? sv : ev;
                k8[u] = (i < k) ? v : INFV;
                c8[u] = 0;
            }
            for (int j = 0; j < dg; ++j) {
                float xv = sval[nb[j] * DD + d];
                #pragma unroll
                for (int u = 0; u < 8; ++u) c8[u] += (xv < k8[u]);
            }
            if (ne >= 1) {
                #pragma unroll
                for (int u = 0; u < 8; ++u) c8[u] += (exv0 < k8[u]);
            }
            if (ne == 2) {
                #pragma unroll
                for (int u = 0; u < 8; ++u) c8[u] += (exv1 < k8[u]);
            }
            #pragma unroll
            for (int u = 0; u < 8; ++u) {
                if (!done && (i0 + u) < k && c8[u] == r) { result = k8[u]; done = true; }
            }
        }
        if (__ballot(!done)) {  // duplicates across rank: exact multiset selection
            for (int i0 = 0; __ballot(!done && i0 < k); i0 += 4) {
                float k4[4]; uint32_t lt4[4], le4[4];
                #pragma unroll
                for (int u = 0; u < 4; ++u) {
                    int i = i0 + u;
                    float sv = sval[nb[i & 127] * DD + d];
                    float ev = ((i - dg) == 0) ? exv0 : exv1;
                    float v = (i < dg) ? sv : ev;
                    k4[u] = (i < k) ? v : INFV;
                    lt4[u] = 0; le4[u] = 0;
                }
                for (int j = 0; j < dg; ++j) {
                    float xv = sval[nb[j] * DD + d];
                    #pragma unroll
                    for (int u = 0; u < 4; ++u) { lt4[u] += (xv < k4[u]); le4[u] += (xv <= k4[u]); }
                }
                if (ne >= 1) {
                    #pragma unroll
                    for (int u = 0; u < 4; ++u) { lt4[u] += (exv0 < k4[u]); le4[u] += (exv0 <= k4[u]); }
                }
                if (ne == 2) {
                    #pragma unroll
                    for (int u = 0; u < 4; ++u) { lt4[u] += (exv1 < k4[u]); le4[u] += (exv1 <= k4[u]); }
                }
                #pragma unroll
                for (int u = 0; u < 4; ++u) {
                    if (!done && (i0 + u) < k && lt4[u] <= r && r < le4[u]) {
                        result = k4[u]; done = true;
                    }
                }
            }
        }
    }

    out[(((size_t)(b * TT + t) * NN) + n) * DD + d] = result;
}

extern "C" void kernel_launch(void* const* d_in, const int* in_sizes, int n_in,
                              void* d_out, int out_size, void* d_ws, size_t ws_size,
                              hipStream_t stream) {
    const float* xs = (const float*)d_in[0];
    const int* A = (const int*)d_in[1];
    float* out = (float*)d_out;

    // workspace layout: deg[128] int (512 B) | nbr[128][128] u8 (16 KB)
    int* deg = (int*)d_ws;
    uint8_t* nbr = (uint8_t*)d_ws + 512;

    build_adj_kernel<<<NN, 64, 0, stream>>>(A, deg, nbr);
    median_kernel<<<NBLK, TPB, 0, stream>>>(xs, deg, nbr, out);
}

// Round 3
// 122.251 us; speedup vs baseline: 1.0471x; 1.0471x over previous
//
#include <hip/hip_runtime.h>
#include <stdint.h>
#include <math.h>

// Problem shape (fixed by reference): xs [B,T,N,D] fp32, A [1,N,N] int32
#define BB 4
#define TT 32
#define NN 128
#define DD 32
#define NPB 16                       // nodes per block (16 nodes x 32 d = 512 threads)
#define TPB (NPB * DD)               // 512 threads
#define NBLK (BB * TT * (NN / NPB))  // 1024 blocks = exactly 4 per CU
#define CAP 16                       // band list capacity; selected-bin overflow -> exact fallback
#define SSTR (TPB + 4)               // 516: slist column stride (scatters banks across slots)

// Temporal-candidate sentinel ids in the u8 band list (real ids are 0..127).
#define SID_PREV 0xFEu
#define SID_NEXT 0xFFu

// Arithmetic 8-bin partition of the value axis. ANY monotone non-decreasing
// bin function gives exact rank selection (equal values -> equal bins, so
// bins partition the multiset in value order). Bins ~[-0.8+0.2b, -0.6+0.2b),
// ends open via clamp. Median of ~66 N(0,1) lands in interior bins with
// count <= CAP except ~1e-5/lane -> fallback is exact anyway.
__device__ __forceinline__ int bin8(float x) {
    int i = (int)fmaf(x, 5.0f, 4.0f);   // trunc; monotone non-decreasing
    i = i < 0 ? 0 : i;
    return i > 7 ? 7 : i;
}

// Build per-node compacted neighbor lists from A (+ implicit self loop).
__global__ __launch_bounds__(64) void build_adj_kernel(const int* __restrict__ A,
                                                       int* __restrict__ deg,
                                                       uint8_t* __restrict__ nbr) {
    const int n = blockIdx.x;
    const int lane = threadIdx.x;  // 0..63
    const int* arow = A + n * NN;
    uint8_t* row = nbr + n * NN;
    const int j0 = lane, j1 = lane + 64;
    const bool b0 = (arow[j0] != 0) || (j0 == n);
    const bool b1 = (arow[j1] != 0) || (j1 == n);
    const unsigned long long m0 = __ballot(b0);
    const unsigned long long m1 = __ballot(b1);
    const unsigned long long lmask = (1ULL << lane) - 1ULL;
    const int c0 = __popcll(m0);
    if (b0) row[__popcll(m0 & lmask)] = (uint8_t)j0;
    if (b1) row[c0 + __popcll(m1 & lmask)] = (uint8_t)j1;
    if (lane == 0) deg[n] = c0 + __popcll(m1);
}

// R3 == R2 resubmit (R2 bench was an infra failure, no data): two-pronged
// attack after flat R1 (Occ 18.7%, VALUBusy 39%, HBM 0.5%):
//  (1) LDS 36.4KB -> 31.4KB (u8 slist + stride-516 columns): if residency was
//      LDS-pool-limited, blocks/CU doubles.
//  (2) sbin: per-element 3-bit bin precomputed ONCE at stage time; A1/A2 read
//      1 byte instead of f32+bin8 (~500 VALU/thread saved, shorter dep chain),
//      and neighbor loops unrolled 8-deep (8 ds_read_u8 in flight vs 4).
// No waves/EU hint: a prior round showed it forces spills (2x regression).
__global__ __launch_bounds__(TPB) void median_kernel(const float* __restrict__ xs,
                                                     const int* __restrict__ deg,
                                                     const uint8_t* __restrict__ nbr,
                                                     float* __restrict__ out) {
    __shared__ float sval[NN * DD];             // 16 KB: current frame values
    __shared__ uint8_t sbin[NN * DD];           // 4 KB: per-element bin (0..7)
    __shared__ uint32_t snbr_w[NPB * NN / 4];   // 2 KB: neighbor id lists (u8)
    __shared__ int sdeg[NPB];
    __shared__ uint8_t slist[(CAP + 1) * SSTR]; // 8.8 KB: band member IDS, column-major

    const int tid = threadIdx.x;
    // Bijective XCD swizzle (NBLK % 8 == 0): each XCD gets a contiguous chunk
    // of 128 logical blocks = 16 whole frames -> frame re-reads are L2-local.
    const int bid = blockIdx.x;
    const int g = ((bid & 7) << 7) | (bid >> 3);
    const int ng = g & (NN / NPB - 1);       // % 8
    const int t  = (g >> 3) & (TT - 1);      // /8 % 32
    const int b  = g >> 8;                   // /256
    const int n0 = ng * NPB;

    const int d = tid & (DD - 1);
    const int nl = tid >> 5;  // local node 0..15
    const int n = n0 + nl;
    const int pv = (t > 0) ? 1 : 0;        // wave-uniform
    const int nv = (t < TT - 1) ? 1 : 0;   // wave-uniform
    const int ne = pv + nv;

    // temporal candidates as floats (coalesced; issued before the barrier)
    float exv0 = 0.0f, exv1 = 0.0f;
    if (pv) exv0 = xs[(((size_t)(b * TT + t - 1) * NN) + n) * DD + d];
    if (nv) {
        float v = xs[(((size_t)(b * TT + t + 1) * NN) + n) * DD + d];
        if (pv) exv1 = v; else exv0 = v;
    }

    // stage current frame (float4 coalesced) + per-element bins (u32-packed)
    const float4* src4 = (const float4*)(xs + ((size_t)(b * TT + t) * NN) * DD);
    #pragma unroll
    for (int s = 0; s < 2; ++s) {
        int i4 = tid + (s << 9);
        float4 f = src4[i4];
        ((float4*)sval)[i4] = f;
        uint32_t pk = (uint32_t)bin8(f.x) | ((uint32_t)bin8(f.y) << 8)
                    | ((uint32_t)bin8(f.z) << 16) | ((uint32_t)bin8(f.w) << 24);
        ((uint32_t*)sbin)[i4] = pk;
    }
    snbr_w[tid] = ((const uint32_t*)(nbr + (size_t)n0 * NN))[tid];  // exactly 512 words
    if (tid < NPB) sdeg[tid] = deg[n0 + tid];
    __syncthreads();

    const int dg = sdeg[nl];
    const int k = dg + ne;
    const uint32_t r = (uint32_t)((k - 1) >> 1);  // lower-median rank (0-based)
    const uint8_t* nb = (const uint8_t*)snbr_w + nl * NN;
    const float INFV = __uint_as_float(0x7F800000u);

    // per-element bin lookup: 1 byte, ~<=2-way banked (id uniform per 32-group)
    auto gbin = [&](uint32_t id) -> int { return (int)sbin[id * DD + d]; };
    const int be0 = bin8(exv0);
    const int be1 = bin8(exv1);

    // ---- A1: one-pass 8-bin histogram, packed 8x8-bit in u64; unroll 8 ----
    unsigned long long pcnt = 0ull;
    {
        int j = 0;
        for (; j + 8 <= dg; j += 8) {
            uint32_t nw0 = *(const uint32_t*)(nb + j);
            uint32_t nw1 = *(const uint32_t*)(nb + j + 4);
            int bsv[8];
            #pragma unroll
            for (int q = 0; q < 4; ++q) {
                bsv[q]     = gbin((nw0 >> (q * 8)) & 0xFFu);
                bsv[q + 4] = gbin((nw1 >> (q * 8)) & 0xFFu);
            }
            #pragma unroll
            for (int q = 0; q < 8; ++q) pcnt += 1ull << (bsv[q] * 8);
        }
        for (; j < dg; ++j) pcnt += 1ull << (gbin(nb[j]) * 8);
        if (ne >= 1) pcnt += 1ull << (be0 * 8);
        if (ne == 2) pcnt += 1ull << (be1 * 8);
    }

    // ---- prefix over 8 byte-counts; select bin containing rank r ----
    uint32_t cum = 0, lowcnt = 0, mexp = 0;
    int selbin = -1;
    #pragma unroll
    for (int bb = 0; bb < 8; ++bb) {
        uint32_t bc = (uint32_t)(pcnt >> (bb * 8)) & 0xFFu;
        uint32_t nc = cum + bc;
        if (selbin < 0 && r < nc) { selbin = bb; lowcnt = cum; mexp = bc; }
        cum = nc;
    }
    const bool fb = (mexp > CAP);          // only fallback: band too big
    const uint32_t rp = r - lowcnt;        // rank within band
    const int storebin = fb ? -1 : selbin; // fb lanes store nothing (mc stays 0)

    // ---- A2: branchless compaction of band member IDS (always-store; the
    // member's write is always the last write to its slot before mc advances).
    // Bin bytes batched 8-deep into registers before the serial mc chain. ----
    int mc = 0;
    {
        int j = 0;
        for (; j + 8 <= dg; j += 8) {
            uint32_t nw0 = *(const uint32_t*)(nb + j);
            uint32_t nw1 = *(const uint32_t*)(nb + j + 4);
            uint32_t ids[8]; int bsv[8];
            #pragma unroll
            for (int q = 0; q < 4; ++q) {
                ids[q]     = (nw0 >> (q * 8)) & 0xFFu;
                ids[q + 4] = (nw1 >> (q * 8)) & 0xFFu;
            }
            #pragma unroll
            for (int q = 0; q < 8; ++q) bsv[q] = gbin(ids[q]);
            #pragma unroll
            for (int q = 0; q < 8; ++q) {
                int slot = mc > CAP ? CAP : mc;
                slist[slot * SSTR + tid] = (uint8_t)ids[q];
                mc += (bsv[q] == storebin);
            }
        }
        for (; j < dg; ++j) {
            uint32_t id = nb[j];
            int bv = gbin(id);
            int slot = mc > CAP ? CAP : mc;
            slist[slot * SSTR + tid] = (uint8_t)id;
            mc += (bv == storebin);
        }
        if (ne >= 1) {
            int slot = mc > CAP ? CAP : mc;
            slist[slot * SSTR + tid] = (uint8_t)SID_PREV;
            mc += (be0 == storebin);
        }
        if (ne == 2) {
            int slot = mc > CAP ? CAP : mc;
            slist[slot * SSTR + tid] = (uint8_t)SID_NEXT;
            mc += (be1 == storebin);
        }
    }

    // band value fetch: id & 127 keeps even garbage/sentinel ids in-bounds;
    // sentinels override via cndmask. slist column tid is thread-private, so
    // no barrier needed between A2 writes and these reads (same-thread lgkmcnt).
    auto bandval = [&](int e) -> float {
        uint32_t id = slist[e * SSTR + tid];
        float v = sval[(id & 127u) * DD + d];
        v = (id == SID_PREV) ? exv0 : v;
        v = (id == SID_NEXT) ? exv1 : v;
        return v;
    };

    // ---- B: single W=16 counting pass over the band (mc <= CAP) ----
    float ki[CAP];
    uint32_t cn[CAP];
    #pragma unroll
    for (int u = 0; u < CAP; ++u) {
        float v = bandval(u);
        ki[u] = (u < mc) ? v : INFV;
        cn[u] = 0;
    }
    int mm = mc;  // wave max -> uniform trip count
    #pragma unroll
    for (int off = 32; off; off >>= 1) {
        int o = __shfl_xor(mm, off);
        mm = mm > o ? mm : o;
    }
    {
        int j = 0;
        for (; j + 2 <= mm; j += 2) {  // unroll 2: two independent LDS chains
            float x0 = bandval(j);
            float x1 = bandval(j + 1);
            x0 = (j < mc) ? x0 : INFV;      // INF < ki never true
            x1 = (j + 1 < mc) ? x1 : INFV;
            #pragma unroll
            for (int u = 0; u < CAP; ++u) cn[u] += (x0 < ki[u]) + (x1 < ki[u]);
        }
        if (j < mm) {
            float x = bandval(j);
            x = (j < mc) ? x : INFV;
            #pragma unroll
            for (int u = 0; u < CAP; ++u) cn[u] += (x < ki[u]);
        }
    }
    float result = 0.0f;
    bool found = fb;
    #pragma unroll
    for (int u = 0; u < CAP; ++u) {
        // strict-below count == rp identifies rank-rp exactly (unique per value)
        if (!found && u < mc && cn[u] == rp) { result = ki[u]; found = true; }
    }

    // ---- duplicate-median pass (exact multiset lower-median; ~never runs) ----
    if (__ballot(!found)) {
        uint32_t eq[CAP];
        #pragma unroll
        for (int u = 0; u < CAP; ++u) eq[u] = 0;
        for (int j = 0; j < mm; ++j) {
            float x = bandval(j);
            x = (j < mc) ? x : INFV;  // INF == finite ki is false
            #pragma unroll
            for (int u = 0; u < CAP; ++u) eq[u] += (x == ki[u]);
        }
        #pragma unroll
        for (int u = 0; u < CAP; ++u) {
            if (!found && u < mc && cn[u] <= rp && rp < cn[u] + eq[u]) {
                result = ki[u]; found = true;
            }
        }
    }

    // ---- full fallback (band > CAP; ~1e-5 of lanes): exact over all k ----
    if (__ballot(fb)) {
        bool done = !fb;
        for (int i0 = 0; __ballot(!done && i0 < k); i0 += 8) {
            float k8[8]; uint32_t c8[8];
            #pragma unroll
            for (int u = 0; u < 8; ++u) {
                int i = i0 + u;
                float sv = sval[nb[i & 127] * DD + d];
                float ev = ((i - dg) == 0) ? exv0 : exv1;
                float v = (i < dg) ? sv : ev;
                k8[u] = (i < k) ? v : INFV;
                c8[u] = 0;
            }
            for (int j = 0; j < dg; ++j) {
                float xv = sval[nb[j] * DD + d];
                #pragma unroll
                for (int u = 0; u < 8; ++u) c8[u] += (xv < k8[u]);
            }
            if (ne >= 1) {
                #pragma unroll
                for (int u = 0; u < 8; ++u) c8[u] += (exv0 < k8[u]);
            }
            if (ne == 2) {
                #pragma unroll
                for (int u = 0; u < 8; ++u) c8[u] += (exv1 < k8[u]);
            }
            #pragma unroll
            for (int u = 0; u < 8; ++u) {
                if (!done && (i0 + u) < k && c8[u] == r) { result = k8[u]; done = true; }
            }
        }
        if (__ballot(!done)) {  // duplicates across rank: exact multiset selection
            for (int i0 = 0; __ballot(!done && i0 < k); i0 += 4) {
                float k4[4]; uint32_t lt4[4], le4[4];
                #pragma unroll
                for (int u = 0; u < 4; ++u) {
                    int i = i0 + u;
                    float sv = sval[nb[i & 127] * DD + d];
                    float ev = ((i - dg) == 0) ? exv0 : exv1;
                    float v = (i < dg) ? sv : ev;
                    k4[u] = (i < k) ? v : INFV;
                    lt4[u] = 0; le4[u] = 0;
                }
                for (int j = 0; j < dg; ++j) {
                    float xv = sval[nb[j] * DD + d];
                    #pragma unroll
                    for (int u = 0; u < 4; ++u) { lt4[u] += (xv < k4[u]); le4[u] += (xv <= k4[u]); }
                }
                if (ne >= 1) {
                    #pragma unroll
                    for (int u = 0; u < 4; ++u) { lt4[u] += (exv0 < k4[u]); le4[u] += (exv0 <= k4[u]); }
                }
                if (ne == 2) {
                    #pragma unroll
                    for (int u = 0; u < 4; ++u) { lt4[u] += (exv1 < k4[u]); le4[u] += (exv1 <= k4[u]); }
                }
                #pragma unroll
                for (int u = 0; u < 4; ++u) {
                    if (!done && (i0 + u) < k && lt4[u] <= r && r < le4[u]) {
                        result = k4[u]; done = true;
                    }
                }
            }
        }
    }

    out[(((size_t)(b * TT + t) * NN) + n) * DD + d] = result;
}

extern "C" void kernel_launch(void* const* d_in, const int* in_sizes, int n_in,
                              void* d_out, int out_size, void* d_ws, size_t ws_size,
                              hipStream_t stream) {
    const float* xs = (const float*)d_in[0];
    const int* A = (const int*)d_in[1];
    float* out = (float*)d_out;

    // workspace layout: deg[128] int (512 B) | nbr[128][128] u8 (16 KB)
    int* deg = (int*)d_ws;
    uint8_t* nbr = (uint8_t*)d_ws + 512;

    build_adj_kernel<<<NN, 64, 0, stream>>>(A, deg, nbr);
    median_kernel<<<NBLK, TPB, 0, stream>>>(xs, deg, nbr, out);
}